// Round 4
// baseline (126.215 us; speedup 1.0000x reference)
//
#include <hip/hip_runtime.h>
#include <hip/hip_bf16.h>

#define BATCH  16384
#define FDIM   256
#define EDIM   128
#define KN     32
#define NNODES 100000

typedef __bf16 bf16x8 __attribute__((ext_vector_type(8)));
typedef float  f32x4  __attribute__((ext_vector_type(4)));

__device__ __forceinline__ unsigned short f2bf(float x) {
    return __builtin_bit_cast(unsigned short, (__bf16)x);
}
__device__ __forceinline__ float bflo(unsigned v) {
    return __builtin_bit_cast(float, v << 16);
}
__device__ __forceinline__ float bfhi(unsigned v) {
    return __builtin_bit_cast(float, v & 0xffff0000u);
}

// ---------- ws layout ----------
// S[NNODES][128] bf16  (self head:  F @ W[0:256,:])
// P[NNODES][128] bf16  (neigh head: F @ W[256:512,:])
// wbt2: combined B^T, plain row-major [j=256][k=256] bf16 (j = output col; j<128 -> S, else P)
#define SP_BYTES   ((size_t)NNODES * 256)
#define WBT2_BYTES ((size_t)256 * 256 * 2)
#define NEW_WS     (2 * SP_BYTES + WBT2_BYTES)

// ---------------- kernel: W[512][128] f32 -> wbt2[j][k] bf16 ----------------
// Wc[k][j] = (j<128) ? W[k][j] : W[k+256][j-128],  k,j in [0,256)
__global__ void conv_w2(const float* __restrict__ weight, char* __restrict__ wbt)
{
    const int gid = blockIdx.x * 256 + threadIdx.x;   // 8192 threads
    const int j   = gid >> 5;          // 0..255
    const int g   = gid & 31;          // k-granule of 8
    union { unsigned short u[8]; uint4 v; } p;
    #pragma unroll
    for (int e = 0; e < 8; ++e) {
        const int k = g * 8 + e;
        const float w = (j < 128) ? weight[(size_t)k * EDIM + j]
                                  : weight[(size_t)(k + 256) * EDIM + (j - 128)];
        p.u[e] = f2bf(w);
    }
    *(uint4*)(wbt + (size_t)j * 512 + g * 16) = p.v;
}

// ---------------- kernel: proj2  S|P = F @ Wc  (no LDS, no barriers) ----------------
// block = 32 rows x 256 cols, 4 waves; wave w owns combined cols [w*64, w*64+64)
// (w=0,1 -> S cols 0..127 ; w=2,3 -> P cols 0..127)
// B-panel held in registers (per K-half: 4 n-tiles x 4 k-slices = 16 uint4)
// A-fragments loaded straight from feat (f32) and converted in-register.
__global__ __launch_bounds__(256, 3)
void proj2(const float* __restrict__ feat, const char* __restrict__ wbt,
           char* __restrict__ Sb, char* __restrict__ Pb)
{
    const int t    = threadIdx.x;
    const int lane = t & 63;
    const int w    = t >> 6;
    const int q    = lane >> 4;        // k-subgroup (0..3)
    const int p    = lane & 15;        // A row / B col within tile
    const int m0   = blockIdx.x * 32;

    f32x4 acc[2][4];
    #pragma unroll
    for (int m = 0; m < 2; ++m)
        #pragma unroll
        for (int n = 0; n < 4; ++n) acc[m][n] = (f32x4){0.f, 0.f, 0.f, 0.f};

    #pragma unroll
    for (int h = 0; h < 2; ++h) {          // K halves: k in [h*128, h*128+128)
        // B fragments for this half: col j = w*64 + n*16 + p, k = h*128 + s*32 + q*8 (+0..7)
        uint4 bf[4][4];
        #pragma unroll
        for (int n = 0; n < 4; ++n)
            #pragma unroll
            for (int s = 0; s < 4; ++s)
                bf[n][s] = *(const uint4*)(wbt + (size_t)(w * 64 + n * 16 + p) * 512
                                               + (h * 128 + s * 32 + q * 8) * 2);

        #pragma unroll
        for (int m = 0; m < 2; ++m) {
            const float* ar = feat + (size_t)(m0 + m * 16 + p) * FDIM + h * 128 + q * 8;
            bf16x8 af[4];
            #pragma unroll
            for (int s = 0; s < 4; ++s) {
                const float4 x = *(const float4*)(ar + s * 32);
                const float4 y = *(const float4*)(ar + s * 32 + 4);
                af[s][0] = (__bf16)x.x; af[s][1] = (__bf16)x.y;
                af[s][2] = (__bf16)x.z; af[s][3] = (__bf16)x.w;
                af[s][4] = (__bf16)y.x; af[s][5] = (__bf16)y.y;
                af[s][6] = (__bf16)y.z; af[s][7] = (__bf16)y.w;
            }
            #pragma unroll
            for (int s = 0; s < 4; ++s)
                #pragma unroll
                for (int n = 0; n < 4; ++n)
                    acc[m][n] = __builtin_amdgcn_mfma_f32_16x16x32_bf16(
                        af[s], __builtin_bit_cast(bf16x8, bf[n][s]), acc[m][n], 0, 0, 0);
        }
    }

    // epilogue: bf16 stores; wave-uniform S/P split
    char* base   = (w < 2) ? Sb : Pb;
    const int cw = (w & 1) * 64;
    #pragma unroll
    for (int m = 0; m < 2; ++m)
        #pragma unroll
        for (int n = 0; n < 4; ++n)
            #pragma unroll
            for (int j = 0; j < 4; ++j) {
                const int row = m0 + m * 16 + q * 4 + j;
                *(unsigned short*)(base + (size_t)row * 256 + (cw + n * 16 + p) * 2)
                    = f2bf(acc[m][n][j]);
            }
}

// ---------------- kernel: gather2  out[b] = relu(S[nodes[b]] + mean_k P[neigh]) ------
__global__ __launch_bounds__(256, 4)
void gather2(const int* __restrict__ nodes, const int* __restrict__ neigh,
             const char* __restrict__ Sb, const char* __restrict__ Pb,
             float* __restrict__ out)
{
    const int lane = threadIdx.x & 63;
    const int b    = __builtin_amdgcn_readfirstlane(blockIdx.x * 4 + (threadIdx.x >> 6));

    const int nid = __builtin_amdgcn_readfirstlane(nodes[b]);
    const unsigned sv = *(const unsigned*)(Sb + (size_t)nid * 256 + lane * 4);

    const int* nb = neigh + (size_t)b * KN;
    float a0 = 0.f, a1 = 0.f;
    #pragma unroll
    for (int k = 0; k < KN; k += 8) {
        int id[8];
        #pragma unroll
        for (int j = 0; j < 8; ++j)
            id[j] = __builtin_amdgcn_readfirstlane(nb[k + j]);
        unsigned v[8];
        #pragma unroll
        for (int j = 0; j < 8; ++j)
            v[j] = *(const unsigned*)(Pb + (size_t)id[j] * 256 + lane * 4);
        #pragma unroll
        for (int j = 0; j < 8; ++j) {
            a0 += bflo(v[j]);
            a1 += bfhi(v[j]);
        }
    }

    const float inv = 1.0f / 32.0f;
    float o0 = bflo(sv) + a0 * inv;
    float o1 = bfhi(sv) + a1 * inv;
    o0 = o0 > 0.f ? o0 : 0.f;
    o1 = o1 > 0.f ? o1 : 0.f;
    ((float2*)out)[(size_t)b * 64 + lane] = make_float2(o0, o1);
}

// ================= fallback path (round-2): cat + gemm =================
#define CAT_BYTES ((size_t)BATCH * 1024)
#define WB_BYTES  ((size_t)512 * EDIM * 2)

__global__ void conv_w(const float* __restrict__ weight, char* __restrict__ wb)
{
    const int t  = blockIdx.x * 256 + threadIdx.x;
    const int c  = t & 127;
    const int g  = (t >> 7) & 15;
    const int kt = t >> 11;
    union { unsigned short u[8]; uint4 v; } p;
    #pragma unroll
    for (int j = 0; j < 8; ++j)
        p.u[j] = f2bf(weight[(size_t)(kt * 128 + g * 8 + j) * EDIM + c]);
    *(uint4*)(wb + (size_t)kt * 32768 + c * 256 + ((g * 16) ^ ((c & 7) << 4))) = p.v;
}

__global__ __launch_bounds__(256, 4)
void gather_agg(const int* __restrict__ nodes, const int* __restrict__ neigh,
                const float* __restrict__ feat, char* __restrict__ cat)
{
    const int lane = threadIdx.x & 63;
    const int row  = __builtin_amdgcn_readfirstlane(blockIdx.x * 4 + (threadIdx.x >> 6));
    const int s    = (row & 7) << 4;
    const int nid  = __builtin_amdgcn_readfirstlane(nodes[row]);
    float4 sf = ((const float4*)(feat + (size_t)nid * FDIM))[lane];
    const int* nb = neigh + (size_t)row * KN;
    float ax = 0.f, ay = 0.f, az = 0.f, aw = 0.f;
    #pragma unroll
    for (int k = 0; k < KN; k += 8) {
        int id[8];
        #pragma unroll
        for (int j = 0; j < 8; ++j) id[j] = __builtin_amdgcn_readfirstlane(nb[k + j]);
        float4 v[8];
        #pragma unroll
        for (int j = 0; j < 8; ++j) v[j] = ((const float4*)(feat + (size_t)id[j] * FDIM))[lane];
        #pragma unroll
        for (int j = 0; j < 8; ++j) { ax += v[j].x; ay += v[j].y; az += v[j].z; aw += v[j].w; }
    }
    char* rowp = cat + (size_t)row * 1024;
    {
        union { unsigned short u[4]; uint2 v; } p;
        p.u[0] = f2bf(sf.x); p.u[1] = f2bf(sf.y); p.u[2] = f2bf(sf.z); p.u[3] = f2bf(sf.w);
        *(uint2*)(rowp + ((lane * 8) ^ s)) = p.v;
    }
    {
        const float inv = 1.0f / 32.0f;
        union { unsigned short u[4]; uint2 v; } p;
        p.u[0] = f2bf(ax * inv); p.u[1] = f2bf(ay * inv);
        p.u[2] = f2bf(az * inv); p.u[3] = f2bf(aw * inv);
        *(uint2*)(rowp + ((512 + lane * 8) ^ s)) = p.v;
    }
}

__global__ __launch_bounds__(256, 2)
void gemm_out(const char* __restrict__ cat, const char* __restrict__ wb,
              float* __restrict__ out)
{
    __shared__ __align__(16) char lds_a[64 * 256];
    __shared__ __align__(16) char lds_b[128 * 256];
    const int t    = threadIdx.x;
    const int lane = t & 63;
    const int w    = t >> 6;
    const int m0   = blockIdx.x * 64;
    const int r0   = w * 16;
    const int q    = lane >> 4;
    const int p    = lane & 15;
    const int ps   = (p & 7) << 4;
    f32x4 acc[8];
    #pragma unroll
    for (int n = 0; n < 8; ++n) acc[n] = (f32x4){0.f, 0.f, 0.f, 0.f};
    for (int kt = 0; kt < 4; ++kt) {
        #pragma unroll
        for (int i = 0; i < 4; ++i) {
            const int g   = i * 256 + t;
            const int row = g >> 4;
            const int x   = (g & 15) * 16;
            __builtin_amdgcn_global_load_lds(
                (const void*)(cat + (size_t)(m0 + row) * 1024 + kt * 256 + x),
                (void*)(lds_a + g * 16), 16, 0, 0);
        }
        #pragma unroll
        for (int i = 0; i < 8; ++i) {
            const int g = i * 256 + t;
            __builtin_amdgcn_global_load_lds(
                (const void*)(wb + (size_t)kt * 32768 + g * 16),
                (void*)(lds_b + g * 16), 16, 0, 0);
        }
        __syncthreads();
        #pragma unroll
        for (int kk = 0; kk < 4; ++kk) {
            const int xo = (kk * 64 + q * 16);
            bf16x8 a = *(const bf16x8*)(lds_a + (r0 + p) * 256 + (xo ^ ps));
            #pragma unroll
            for (int n = 0; n < 8; ++n) {
                bf16x8 b = *(const bf16x8*)(lds_b + (n * 16 + p) * 256 + (xo ^ ps));
                acc[n] = __builtin_amdgcn_mfma_f32_16x16x32_bf16(a, b, acc[n], 0, 0, 0);
            }
        }
        __syncthreads();
    }
    #pragma unroll
    for (int n = 0; n < 8; ++n) {
        #pragma unroll
        for (int j = 0; j < 4; ++j) {
            const float v = acc[n][j];
            out[(size_t)(m0 + r0 + q * 4 + j) * EDIM + n * 16 + p] = v > 0.f ? v : 0.f;
        }
    }
}

extern "C" void kernel_launch(void* const* d_in, const int* in_sizes, int n_in,
                              void* d_out, int out_size, void* d_ws, size_t ws_size,
                              hipStream_t stream) {
    const int*   nodes  = (const int*)d_in[0];
    const int*   neigh  = (const int*)d_in[1];
    const float* feat   = (const float*)d_in[2];
    const float* weight = (const float*)d_in[3];
    float*       out    = (float*)d_out;

    if (ws_size >= NEW_WS) {
        char* Sb  = (char*)d_ws;
        char* Pb  = (char*)d_ws + SP_BYTES;
        char* wbt = (char*)d_ws + 2 * SP_BYTES;
        conv_w2<<<32, 256, 0, stream>>>(weight, wbt);
        proj2<<<NNODES / 32, 256, 0, stream>>>(feat, wbt, Sb, Pb);
        gather2<<<BATCH / 4, 256, 0, stream>>>(nodes, neigh, Sb, Pb, out);
    } else {
        char* cat = (char*)d_ws;
        char* wb  = (char*)d_ws + CAT_BYTES;
        conv_w<<<32, 256, 0, stream>>>(weight, wb);
        gather_agg<<<BATCH / 4, 256, 0, stream>>>(nodes, neigh, feat, cat);
        gemm_out<<<BATCH / 64, 256, 0, stream>>>(cat, wb, out);
    }
}

// Round 5
// 66.403 us; speedup vs baseline: 1.9008x; 1.9008x over previous
//
#include <hip/hip_runtime.h>
#include <hip/hip_bf16.h>

#define BATCH  16384
#define FDIM   256
#define EDIM   128
#define KN     32
#define NNODES 100000

typedef __bf16 bf16x8 __attribute__((ext_vector_type(8)));
typedef float  f32x4  __attribute__((ext_vector_type(4)));

__device__ __forceinline__ unsigned short f2bf(float x) {
    return __builtin_bit_cast(unsigned short, (__bf16)x);
}
__device__ __forceinline__ float bflo(unsigned v) {
    return __builtin_bit_cast(float, v << 16);
}
__device__ __forceinline__ float bfhi(unsigned v) {
    return __builtin_bit_cast(float, v & 0xffff0000u);
}

// ---------- ws layout ----------
// S[NNODES][128] bf16, P[NNODES][128] bf16
// wbt: combined B^T bf16, 4 kt-chunks of [256 j][128 B] (k = kt*64 + 0..63),
//      16B granules XOR'd by (j&7)<<4 (pre-swizzled for linear global_load_lds)
#define SP_BYTES  ((size_t)NNODES * 256)
#define WBT_BYTES ((size_t)4 * 256 * 128)
#define NEW_WS    (2 * SP_BYTES + WBT_BYTES)

// ---------------- kernel: W[512][128] f32 -> swizzled wbt bf16 ----------------
// Wc[k][j] = (j<128) ? W[k][j] : W[k+256][j-128],  k,j in [0,256)
__global__ void conv_w2(const float* __restrict__ weight, char* __restrict__ wbt)
{
    const int gid = blockIdx.x * 256 + threadIdx.x;   // 8192 granules
    const int kt  = gid >> 11;
    const int rem = gid & 2047;
    const int j   = rem >> 3;
    const int g   = rem & 7;
    union { unsigned short u[8]; uint4 v; } p;
    #pragma unroll
    for (int e = 0; e < 8; ++e) {
        const int k = kt * 64 + g * 8 + e;
        const float w = (j < 128) ? weight[(size_t)k * EDIM + j]
                                  : weight[(size_t)(k + 256) * EDIM + (j - 128)];
        p.u[e] = f2bf(w);
    }
    *(uint4*)(wbt + (size_t)kt * 32768 + j * 128 + ((g * 16) ^ ((j & 7) << 4))) = p.v;
}

// ---------------- kernel: proj3  S|P = F @ Wc ----------------
// 128 rows x 256 cols per block, 8 waves (2m x 4n), BK=64, dbuf LDS,
// global_load_lds staging with counted vmcnt (prefetch alive across barriers).
__global__ __launch_bounds__(512, 1)
void proj3(const float* __restrict__ feat, const char* __restrict__ wbt,
           char* __restrict__ Sb, char* __restrict__ Pb)
{
    // [0,32K)+[32K,64K): A bufs, [128 r][256 B] f32 (16B granules swz by (r&7)<<4)
    // [64K,96K)+[96K,128K): B bufs, [256 j][128 B] bf16 (pre-swizzled in wbt)
    __shared__ __align__(16) char lds[131072];

    const int t    = threadIdx.x;
    const int lane = t & 63;
    const int w    = t >> 6;
    const int wr   = w >> 2;          // 0..1  (row half)
    const int wc   = w & 3;           // 0..3  (col quarter)
    const int q    = lane >> 4;
    const int p    = lane & 15;
    const int m0   = blockIdx.x * 128;

    // staging constants (per thread): 4 A granules + 4 B granules per stage
    const int ga_r[4] = { (0 * 512 + t) >> 4, (1 * 512 + t) >> 4,
                          (2 * 512 + t) >> 4, (3 * 512 + t) >> 4 };
    f32x4 acc[4][4];
    #pragma unroll
    for (int mi = 0; mi < 4; ++mi)
        #pragma unroll
        for (int n = 0; n < 4; ++n) acc[mi][n] = (f32x4){0.f, 0.f, 0.f, 0.f};

#define STAGE(KT, BUF)                                                          \
    do {                                                                        \
        _Pragma("unroll")                                                       \
        for (int i = 0; i < 4; ++i) {                                           \
            const int g = i * 512 + t;                                          \
            const int r = g >> 4;                                               \
            const int x = (g & 15) * 16;                                        \
            int row = m0 + r; if (row > NNODES - 1) row = NNODES - 1;           \
            __builtin_amdgcn_global_load_lds(                                   \
                (const void*)((const char*)feat + (size_t)row * 1024            \
                              + (KT) * 256 + (x ^ ((r & 7) << 4))),             \
                (void*)(lds + (BUF) * 32768 + g * 16), 16, 0, 0);               \
        }                                                                       \
        _Pragma("unroll")                                                       \
        for (int i = 0; i < 4; ++i) {                                           \
            const int g = i * 512 + t;                                          \
            __builtin_amdgcn_global_load_lds(                                   \
                (const void*)(wbt + (size_t)(KT) * 32768 + g * 16),             \
                (void*)(lds + 65536 + (BUF) * 32768 + g * 16), 16, 0, 0);       \
        }                                                                       \
    } while (0)

    STAGE(0, 0);

    #pragma unroll
    for (int kt = 0; kt < 4; ++kt) {
        const int cur = kt & 1;
        if (kt < 3) {
            STAGE(kt + 1, cur ^ 1);
            asm volatile("s_waitcnt vmcnt(8)" ::: "memory");
        } else {
            asm volatile("s_waitcnt vmcnt(0)" ::: "memory");
        }
        __builtin_amdgcn_s_barrier();
        asm volatile("" ::: "memory");

        const char* Ab = lds + cur * 32768;
        const char* Bb = lds + 65536 + cur * 32768;

        #pragma unroll
        for (int kk = 0; kk < 2; ++kk) {
            bf16x8 a[4];
            #pragma unroll
            for (int mi = 0; mi < 4; ++mi) {
                const int r  = wr * 64 + mi * 16 + p;
                const int sw = (r & 7) << 4;
                const f32x4 lo = *(const f32x4*)(Ab + r * 256 + ((kk * 128 + q * 32) ^ sw));
                const f32x4 hi = *(const f32x4*)(Ab + r * 256 + ((kk * 128 + q * 32 + 16) ^ sw));
                a[mi][0] = (__bf16)lo[0]; a[mi][1] = (__bf16)lo[1];
                a[mi][2] = (__bf16)lo[2]; a[mi][3] = (__bf16)lo[3];
                a[mi][4] = (__bf16)hi[0]; a[mi][5] = (__bf16)hi[1];
                a[mi][6] = (__bf16)hi[2]; a[mi][7] = (__bf16)hi[3];
            }
            #pragma unroll
            for (int n = 0; n < 4; ++n) {
                const int j = wc * 64 + n * 16 + p;
                const bf16x8 b = *(const bf16x8*)(Bb + j * 128
                                     + ((kk * 64 + q * 16) ^ ((j & 7) << 4)));
                #pragma unroll
                for (int mi = 0; mi < 4; ++mi)
                    acc[mi][n] = __builtin_amdgcn_mfma_f32_16x16x32_bf16(
                        a[mi], b, acc[mi][n], 0, 0, 0);
            }
        }
        asm volatile("" ::: "memory");
        __builtin_amdgcn_s_barrier();
        asm volatile("" ::: "memory");
    }
#undef STAGE

    // epilogue: bf16 stores; cols wc*64.. : wc<2 -> S, wc>=2 -> P
    char* base    = (wc < 2) ? Sb : Pb;
    const int c0  = (wc & 1) * 64;
    #pragma unroll
    for (int mi = 0; mi < 4; ++mi)
        #pragma unroll
        for (int jj = 0; jj < 4; ++jj) {
            const int row = m0 + wr * 64 + mi * 16 + q * 4 + jj;
            if (row < NNODES) {
                #pragma unroll
                for (int n = 0; n < 4; ++n)
                    *(unsigned short*)(base + (size_t)row * 256 + (c0 + n * 16 + p) * 2)
                        = f2bf(acc[mi][n][jj]);
            }
        }
}

// ---------------- kernel: gather2  out[b] = relu(S[nodes[b]] + mean_k P[neigh]) ------
__global__ __launch_bounds__(256, 4)
void gather2(const int* __restrict__ nodes, const int* __restrict__ neigh,
             const char* __restrict__ Sb, const char* __restrict__ Pb,
             float* __restrict__ out)
{
    const int lane = threadIdx.x & 63;
    const int b    = __builtin_amdgcn_readfirstlane(blockIdx.x * 4 + (threadIdx.x >> 6));

    const int nid = __builtin_amdgcn_readfirstlane(nodes[b]);
    const unsigned sv = *(const unsigned*)(Sb + (size_t)nid * 256 + lane * 4);

    const int* nb = neigh + (size_t)b * KN;
    float a0 = 0.f, a1 = 0.f;
    #pragma unroll
    for (int k = 0; k < KN; k += 8) {
        int id[8];
        #pragma unroll
        for (int j = 0; j < 8; ++j)
            id[j] = __builtin_amdgcn_readfirstlane(nb[k + j]);
        unsigned v[8];
        #pragma unroll
        for (int j = 0; j < 8; ++j)
            v[j] = *(const unsigned*)(Pb + (size_t)id[j] * 256 + lane * 4);
        #pragma unroll
        for (int j = 0; j < 8; ++j) {
            a0 += bflo(v[j]);
            a1 += bfhi(v[j]);
        }
    }

    const float inv = 1.0f / 32.0f;
    float o0 = bflo(sv) + a0 * inv;
    float o1 = bfhi(sv) + a1 * inv;
    o0 = o0 > 0.f ? o0 : 0.f;
    o1 = o1 > 0.f ? o1 : 0.f;
    ((float2*)out)[(size_t)b * 64 + lane] = make_float2(o0, o1);
}

// ================= fallback path (round-2): cat + gemm =================
#define CAT_BYTES ((size_t)BATCH * 1024)
#define WB_BYTES  ((size_t)512 * EDIM * 2)

__global__ void conv_w(const float* __restrict__ weight, char* __restrict__ wb)
{
    const int t  = blockIdx.x * 256 + threadIdx.x;
    const int c  = t & 127;
    const int g  = (t >> 7) & 15;
    const int kt = t >> 11;
    union { unsigned short u[8]; uint4 v; } p;
    #pragma unroll
    for (int j = 0; j < 8; ++j)
        p.u[j] = f2bf(weight[(size_t)(kt * 128 + g * 8 + j) * EDIM + c]);
    *(uint4*)(wb + (size_t)kt * 32768 + c * 256 + ((g * 16) ^ ((c & 7) << 4))) = p.v;
}

__global__ __launch_bounds__(256, 4)
void gather_agg(const int* __restrict__ nodes, const int* __restrict__ neigh,
                const float* __restrict__ feat, char* __restrict__ cat)
{
    const int lane = threadIdx.x & 63;
    const int row  = __builtin_amdgcn_readfirstlane(blockIdx.x * 4 + (threadIdx.x >> 6));
    const int s    = (row & 7) << 4;
    const int nid  = __builtin_amdgcn_readfirstlane(nodes[row]);
    float4 sf = ((const float4*)(feat + (size_t)nid * FDIM))[lane];
    const int* nb = neigh + (size_t)row * KN;
    float ax = 0.f, ay = 0.f, az = 0.f, aw = 0.f;
    #pragma unroll
    for (int k = 0; k < KN; k += 8) {
        int id[8];
        #pragma unroll
        for (int j = 0; j < 8; ++j) id[j] = __builtin_amdgcn_readfirstlane(nb[k + j]);
        float4 v[8];
        #pragma unroll
        for (int j = 0; j < 8; ++j) v[j] = ((const float4*)(feat + (size_t)id[j] * FDIM))[lane];
        #pragma unroll
        for (int j = 0; j < 8; ++j) { ax += v[j].x; ay += v[j].y; az += v[j].z; aw += v[j].w; }
    }
    char* rowp = cat + (size_t)row * 1024;
    {
        union { unsigned short u[4]; uint2 v; } p;
        p.u[0] = f2bf(sf.x); p.u[1] = f2bf(sf.y); p.u[2] = f2bf(sf.z); p.u[3] = f2bf(sf.w);
        *(uint2*)(rowp + ((lane * 8) ^ s)) = p.v;
    }
    {
        const float inv = 1.0f / 32.0f;
        union { unsigned short u[4]; uint2 v; } p;
        p.u[0] = f2bf(ax * inv); p.u[1] = f2bf(ay * inv);
        p.u[2] = f2bf(az * inv); p.u[3] = f2bf(aw * inv);
        *(uint2*)(rowp + ((512 + lane * 8) ^ s)) = p.v;
    }
}

__global__ __launch_bounds__(256, 2)
void gemm_out(const char* __restrict__ cat, const char* __restrict__ wb,
              float* __restrict__ out)
{
    __shared__ __align__(16) char lds_a[64 * 256];
    __shared__ __align__(16) char lds_b[128 * 256];
    const int t    = threadIdx.x;
    const int lane = t & 63;
    const int w    = t >> 6;
    const int m0   = blockIdx.x * 64;
    const int r0   = w * 16;
    const int q    = lane >> 4;
    const int p    = lane & 15;
    const int ps   = (p & 7) << 4;
    f32x4 acc[8];
    #pragma unroll
    for (int n = 0; n < 8; ++n) acc[n] = (f32x4){0.f, 0.f, 0.f, 0.f};
    for (int kt = 0; kt < 4; ++kt) {
        #pragma unroll
        for (int i = 0; i < 4; ++i) {
            const int g   = i * 256 + t;
            const int row = g >> 4;
            const int x   = (g & 15) * 16;
            __builtin_amdgcn_global_load_lds(
                (const void*)(cat + (size_t)(m0 + row) * 1024 + kt * 256 + x),
                (void*)(lds_a + g * 16), 16, 0, 0);
        }
        #pragma unroll
        for (int i = 0; i < 8; ++i) {
            const int g = i * 256 + t;
            __builtin_amdgcn_global_load_lds(
                (const void*)(wb + (size_t)kt * 32768 + g * 16),
                (void*)(lds_b + g * 16), 16, 0, 0);
        }
        __syncthreads();
        #pragma unroll
        for (int kk = 0; kk < 4; ++kk) {
            const int xo = (kk * 64 + q * 16);
            bf16x8 a = *(const bf16x8*)(lds_a + (r0 + p) * 256 + (xo ^ ps));
            #pragma unroll
            for (int n = 0; n < 8; ++n) {
                bf16x8 b = *(const bf16x8*)(lds_b + (n * 16 + p) * 256 + (xo ^ ps));
                acc[n] = __builtin_amdgcn_mfma_f32_16x16x32_bf16(a, b, acc[n], 0, 0, 0);
            }
        }
        __syncthreads();
    }
    #pragma unroll
    for (int n = 0; n < 8; ++n) {
        #pragma unroll
        for (int j = 0; j < 4; ++j) {
            const float v = acc[n][j];
            out[(size_t)(m0 + r0 + q * 4 + j) * EDIM + n * 16 + p] = v > 0.f ? v : 0.f;
        }
    }
}

extern "C" void kernel_launch(void* const* d_in, const int* in_sizes, int n_in,
                              void* d_out, int out_size, void* d_ws, size_t ws_size,
                              hipStream_t stream) {
    const int*   nodes  = (const int*)d_in[0];
    const int*   neigh  = (const int*)d_in[1];
    const float* feat   = (const float*)d_in[2];
    const float* weight = (const float*)d_in[3];
    float*       out    = (float*)d_out;

    if (ws_size >= NEW_WS) {
        char* Sb  = (char*)d_ws;
        char* Pb  = (char*)d_ws + SP_BYTES;
        char* wbt = (char*)d_ws + 2 * SP_BYTES;
        conv_w2<<<32, 256, 0, stream>>>(weight, wbt);
        proj3<<<(NNODES + 127) / 128, 512, 0, stream>>>(feat, wbt, Sb, Pb);
        gather2<<<BATCH / 4, 256, 0, stream>>>(nodes, neigh, Sb, Pb, out);
    } else {
        char* cat = (char*)d_ws;
        char* wb  = (char*)d_ws + CAT_BYTES;
        conv_w<<<32, 256, 0, stream>>>(weight, wb);
        gather_agg<<<BATCH / 4, 256, 0, stream>>>(nodes, neigh, feat, cat);
        gemm_out<<<BATCH / 64, 256, 0, stream>>>(cat, wb, out);
    }
}

// Round 6
// 61.678 us; speedup vs baseline: 2.0464x; 1.0766x over previous
//
#include <hip/hip_runtime.h>
#include <hip/hip_bf16.h>

#define BATCH  16384
#define FDIM   256
#define EDIM   128
#define KN     32
#define NNODES 100000

typedef __bf16 bf16x8 __attribute__((ext_vector_type(8)));
typedef float  f32x4  __attribute__((ext_vector_type(4)));

__device__ __forceinline__ unsigned short f2bf(float x) {
    return __builtin_bit_cast(unsigned short, (__bf16)x);
}
__device__ __forceinline__ float bflo(unsigned v) {
    return __builtin_bit_cast(float, v << 16);
}
__device__ __forceinline__ float bfhi(unsigned v) {
    return __builtin_bit_cast(float, v & 0xffff0000u);
}

// ---------- ws layout ----------
// S[NNODES][128] bf16, P[NNODES][128] bf16
// wbt: combined B^T bf16, 8 kt-chunks (BK=32) of [256 j][64 B],
//      16B granules XOR'd by (j&3)<<4 (pre-swizzled for linear global_load_lds)
#define SP_BYTES  ((size_t)NNODES * 256)
#define WBT_BYTES ((size_t)8 * 256 * 64)
#define NEW_WS    (2 * SP_BYTES + WBT_BYTES)

// ---------------- kernel: W[512][128] f32 -> swizzled wbt bf16 ----------------
// Wc[k][j] = (j<128) ? W[k][j] : W[k+256][j-128],  k,j in [0,256)
__global__ void conv_w2(const float* __restrict__ weight, char* __restrict__ wbt)
{
    const int gid = blockIdx.x * 256 + threadIdx.x;   // 8192 granules
    const int kt  = gid >> 10;         // 0..7
    const int j   = (gid >> 2) & 255;  // 0..255
    const int g   = gid & 3;           // 0..3
    union { unsigned short u[8]; uint4 v; } p;
    #pragma unroll
    for (int e = 0; e < 8; ++e) {
        const int k = kt * 32 + g * 8 + e;
        const float w = (j < 128) ? weight[(size_t)k * EDIM + j]
                                  : weight[(size_t)(k + 256) * EDIM + (j - 128)];
        p.u[e] = f2bf(w);
    }
    *(uint4*)(wbt + (size_t)kt * 16384 + j * 64 + ((g * 16) ^ ((j & 3) << 4))) = p.v;
}

// ---------------- kernel: proj4  S|P = F @ Wc ----------------
// 256 thr / 4 waves; wave = 16 rows x 256 cols; BK=32, 8 kt-steps.
// B: LDS dbuf (2x16KB) via global_load_lds + counted vmcnt.
// A: direct global->reg, prefetched one kt ahead, cvt to bf16 at use.
__global__ __launch_bounds__(256, 4)
void proj4(const float* __restrict__ feat, const char* __restrict__ wbt,
           char* __restrict__ Sb, char* __restrict__ Pb)
{
    __shared__ __align__(16) char ldsB[2][16384];   // [buf][256 j][64 B], swz (j&3)<<4

    const int t    = threadIdx.x;
    const int lane = t & 63;
    const int w    = t >> 6;
    const int q    = lane >> 4;
    const int p    = lane & 15;
    const int m0   = blockIdx.x * 64;

    int arow_i = m0 + w * 16 + p;
    if (arow_i > NNODES - 1) arow_i = NNODES - 1;
    const float* arow = feat + (size_t)arow_i * FDIM;

    f32x4 acc[16];
    #pragma unroll
    for (int n = 0; n < 16; ++n) acc[n] = (f32x4){0.f, 0.f, 0.f, 0.f};

#define STAGEB(KT, BUF)                                                     \
    do {                                                                    \
        _Pragma("unroll")                                                   \
        for (int i = 0; i < 4; ++i) {                                       \
            const int g = i * 256 + t;                                      \
            __builtin_amdgcn_global_load_lds(                               \
                (const void*)(wbt + (size_t)(KT) * 16384 + g * 16),         \
                (void*)(&ldsB[BUF][g * 16]), 16, 0, 0);                     \
        }                                                                   \
    } while (0)

    float4 aLo[8], aHi[8];   // static-indexed after full unroll

    STAGEB(0, 0);
    aLo[0] = *(const float4*)(arow + q * 8);
    aHi[0] = *(const float4*)(arow + q * 8 + 4);

    #pragma unroll
    for (int kt = 0; kt < 8; ++kt) {
        const int cur = kt & 1;
        if (kt < 7) {
            STAGEB(kt + 1, cur ^ 1);
            aLo[kt + 1] = *(const float4*)(arow + (kt + 1) * 32 + q * 8);
            aHi[kt + 1] = *(const float4*)(arow + (kt + 1) * 32 + q * 8 + 4);
            asm volatile("s_waitcnt vmcnt(6)" ::: "memory");
        } else {
            asm volatile("s_waitcnt vmcnt(0)" ::: "memory");
        }
        __builtin_amdgcn_s_barrier();
        __builtin_amdgcn_sched_barrier(0);

        bf16x8 af;
        af[0] = (__bf16)aLo[kt].x; af[1] = (__bf16)aLo[kt].y;
        af[2] = (__bf16)aLo[kt].z; af[3] = (__bf16)aLo[kt].w;
        af[4] = (__bf16)aHi[kt].x; af[5] = (__bf16)aHi[kt].y;
        af[6] = (__bf16)aHi[kt].z; af[7] = (__bf16)aHi[kt].w;

        #pragma unroll
        for (int n = 0; n < 16; ++n) {
            const int j = n * 16 + p;
            const bf16x8 b = *(const bf16x8*)(&ldsB[cur][j * 64
                                 + ((q * 16) ^ ((j & 3) << 4))]);
            acc[n] = __builtin_amdgcn_mfma_f32_16x16x32_bf16(af, b, acc[n], 0, 0, 0);
        }
        __builtin_amdgcn_sched_barrier(0);
        __builtin_amdgcn_s_barrier();
    }
#undef STAGEB

    // epilogue: n<8 -> S cols, n>=8 -> P cols
    #pragma unroll
    for (int n = 0; n < 16; ++n) {
        char* base = (n < 8) ? Sb : Pb;
        const int col = (n & 7) * 16 + p;
        #pragma unroll
        for (int jj = 0; jj < 4; ++jj) {
            const int row = m0 + w * 16 + q * 4 + jj;
            if (row < NNODES)
                *(unsigned short*)(base + (size_t)row * 256 + col * 2)
                    = f2bf(acc[n][jj]);
        }
    }
}

// ---------------- kernel: gather2  out[b] = relu(S[nodes[b]] + mean_k P[neigh]) ------
__global__ __launch_bounds__(256, 4)
void gather2(const int* __restrict__ nodes, const int* __restrict__ neigh,
             const char* __restrict__ Sb, const char* __restrict__ Pb,
             float* __restrict__ out)
{
    const int lane = threadIdx.x & 63;
    const int b    = __builtin_amdgcn_readfirstlane(blockIdx.x * 4 + (threadIdx.x >> 6));

    const int nid = __builtin_amdgcn_readfirstlane(nodes[b]);
    const unsigned sv = *(const unsigned*)(Sb + (size_t)nid * 256 + lane * 4);

    const int* nb = neigh + (size_t)b * KN;
    float a0 = 0.f, a1 = 0.f;
    #pragma unroll
    for (int k = 0; k < KN; k += 8) {
        int id[8];
        #pragma unroll
        for (int j = 0; j < 8; ++j)
            id[j] = __builtin_amdgcn_readfirstlane(nb[k + j]);
        unsigned v[8];
        #pragma unroll
        for (int j = 0; j < 8; ++j)
            v[j] = *(const unsigned*)(Pb + (size_t)id[j] * 256 + lane * 4);
        #pragma unroll
        for (int j = 0; j < 8; ++j) {
            a0 += bflo(v[j]);
            a1 += bfhi(v[j]);
        }
    }

    const float inv = 1.0f / 32.0f;
    float o0 = bflo(sv) + a0 * inv;
    float o1 = bfhi(sv) + a1 * inv;
    o0 = o0 > 0.f ? o0 : 0.f;
    o1 = o1 > 0.f ? o1 : 0.f;
    ((float2*)out)[(size_t)b * 64 + lane] = make_float2(o0, o1);
}

// ================= fallback path (round-2): cat + gemm =================
#define CAT_BYTES ((size_t)BATCH * 1024)
#define WB_BYTES  ((size_t)512 * EDIM * 2)

__global__ void conv_w(const float* __restrict__ weight, char* __restrict__ wb)
{
    const int t  = blockIdx.x * 256 + threadIdx.x;
    const int c  = t & 127;
    const int g  = (t >> 7) & 15;
    const int kt = t >> 11;
    union { unsigned short u[8]; uint4 v; } p;
    #pragma unroll
    for (int j = 0; j < 8; ++j)
        p.u[j] = f2bf(weight[(size_t)(kt * 128 + g * 8 + j) * EDIM + c]);
    *(uint4*)(wb + (size_t)kt * 32768 + c * 256 + ((g * 16) ^ ((c & 7) << 4))) = p.v;
}

__global__ __launch_bounds__(256, 4)
void gather_agg(const int* __restrict__ nodes, const int* __restrict__ neigh,
                const float* __restrict__ feat, char* __restrict__ cat)
{
    const int lane = threadIdx.x & 63;
    const int row  = __builtin_amdgcn_readfirstlane(blockIdx.x * 4 + (threadIdx.x >> 6));
    const int s    = (row & 7) << 4;
    const int nid  = __builtin_amdgcn_readfirstlane(nodes[row]);
    float4 sf = ((const float4*)(feat + (size_t)nid * FDIM))[lane];
    const int* nb = neigh + (size_t)row * KN;
    float ax = 0.f, ay = 0.f, az = 0.f, aw = 0.f;
    #pragma unroll
    for (int k = 0; k < KN; k += 8) {
        int id[8];
        #pragma unroll
        for (int j = 0; j < 8; ++j) id[j] = __builtin_amdgcn_readfirstlane(nb[k + j]);
        float4 v[8];
        #pragma unroll
        for (int j = 0; j < 8; ++j) v[j] = ((const float4*)(feat + (size_t)id[j] * FDIM))[lane];
        #pragma unroll
        for (int j = 0; j < 8; ++j) { ax += v[j].x; ay += v[j].y; az += v[j].z; aw += v[j].w; }
    }
    char* rowp = cat + (size_t)row * 1024;
    {
        union { unsigned short u[4]; uint2 v; } p;
        p.u[0] = f2bf(sf.x); p.u[1] = f2bf(sf.y); p.u[2] = f2bf(sf.z); p.u[3] = f2bf(sf.w);
        *(uint2*)(rowp + ((lane * 8) ^ s)) = p.v;
    }
    {
        const float inv = 1.0f / 32.0f;
        union { unsigned short u[4]; uint2 v; } p;
        p.u[0] = f2bf(ax * inv); p.u[1] = f2bf(ay * inv);
        p.u[2] = f2bf(az * inv); p.u[3] = f2bf(aw * inv);
        *(uint2*)(rowp + ((512 + lane * 8) ^ s)) = p.v;
    }
}

__global__ __launch_bounds__(256, 2)
void gemm_out(const char* __restrict__ cat, const char* __restrict__ wb,
              float* __restrict__ out)
{
    __shared__ __align__(16) char lds_a[64 * 256];
    __shared__ __align__(16) char lds_b[128 * 256];
    const int t    = threadIdx.x;
    const int lane = t & 63;
    const int w    = t >> 6;
    const int m0   = blockIdx.x * 64;
    const int r0   = w * 16;
    const int q    = lane >> 4;
    const int p    = lane & 15;
    const int ps   = (p & 7) << 4;
    f32x4 acc[8];
    #pragma unroll
    for (int n = 0; n < 8; ++n) acc[n] = (f32x4){0.f, 0.f, 0.f, 0.f};
    for (int kt = 0; kt < 4; ++kt) {
        #pragma unroll
        for (int i = 0; i < 4; ++i) {
            const int g   = i * 256 + t;
            const int row = g >> 4;
            const int x   = (g & 15) * 16;
            __builtin_amdgcn_global_load_lds(
                (const void*)(cat + (size_t)(m0 + row) * 1024 + kt * 256 + x),
                (void*)(lds_a + g * 16), 16, 0, 0);
        }
        #pragma unroll
        for (int i = 0; i < 8; ++i) {
            const int g = i * 256 + t;
            __builtin_amdgcn_global_load_lds(
                (const void*)(wb + (size_t)kt * 32768 + g * 16),
                (void*)(lds_b + g * 16), 16, 0, 0);
        }
        __syncthreads();
        #pragma unroll
        for (int kk = 0; kk < 4; ++kk) {
            const int xo = (kk * 64 + q * 16);
            bf16x8 a = *(const bf16x8*)(lds_a + (r0 + p) * 256 + (xo ^ ps));
            #pragma unroll
            for (int n = 0; n < 8; ++n) {
                bf16x8 b = *(const bf16x8*)(lds_b + (n * 16 + p) * 256 + (xo ^ ps));
                acc[n] = __builtin_amdgcn_mfma_f32_16x16x32_bf16(a, b, acc[n], 0, 0, 0);
            }
        }
        __syncthreads();
    }
    #pragma unroll
    for (int n = 0; n < 8; ++n) {
        #pragma unroll
        for (int j = 0; j < 4; ++j) {
            const float v = acc[n][j];
            out[(size_t)(m0 + r0 + q * 4 + j) * EDIM + n * 16 + p] = v > 0.f ? v : 0.f;
        }
    }
}

extern "C" void kernel_launch(void* const* d_in, const int* in_sizes, int n_in,
                              void* d_out, int out_size, void* d_ws, size_t ws_size,
                              hipStream_t stream) {
    const int*   nodes  = (const int*)d_in[0];
    const int*   neigh  = (const int*)d_in[1];
    const float* feat   = (const float*)d_in[2];
    const float* weight = (const float*)d_in[3];
    float*       out    = (float*)d_out;

    if (ws_size >= NEW_WS) {
        char* Sb  = (char*)d_ws;
        char* Pb  = (char*)d_ws + SP_BYTES;
        char* wbt = (char*)d_ws + 2 * SP_BYTES;
        conv_w2<<<32, 256, 0, stream>>>(weight, wbt);
        proj4<<<(NNODES + 63) / 64, 256, 0, stream>>>(feat, wbt, Sb, Pb);
        gather2<<<BATCH / 4, 256, 0, stream>>>(nodes, neigh, Sb, Pb, out);
    } else {
        char* cat = (char*)d_ws;
        char* wb  = (char*)d_ws + CAT_BYTES;
        conv_w<<<32, 256, 0, stream>>>(weight, wb);
        gather_agg<<<BATCH / 4, 256, 0, stream>>>(nodes, neigh, feat, cat);
        gemm_out<<<BATCH / 64, 256, 0, stream>>>(cat, wb, out);
    }
}